// Round 4
// baseline (432.984 us; speedup 1.0000x reference)
//
#include <hip/hip_runtime.h>
#include <hip/hip_bf16.h>

// Problem constants (fixed by the reference)
#define NPTS 50000   // N data points
#define DIM  256     // feature dim (K of the GEMM)
#define BQ   2048    // batch of queries (M of the GEMM)
#define NPAD 50048   // N padded to multiple of 128 (= 782*64)

#define BK   32
#define LOG2E 1.4426950408889634f

#define NJOBS 782       // n-stripes of 64 rows
#define GRID_MAIN 512   // persistent blocks (2 per CU)

// ---------- fast-path ws layout (float offsets, unchanged from round 3) ----------
//  acc   [0,      2048)
//  x2h   [2048,   4096)   0.5*log2e*||x||^2
//  s2h   [4096,  54144)   0.5*log2e*||s||^2 (NPAD)
//  w     [54144, 104192)  labels*relu(lambdas) (NPAD, 0-padded)
//  xb    [104192, 366336)   bf16 x
//  sb    [366336, 6772480)  bf16 s (NPAD rows, 0-padded)
#define WS_ACC 0
#define WS_X2  2048
#define WS_S2  4096
#define WS_W   54144
#define WS_XB  104192
#define WS_SB  366336
#define WS_TOTAL_BYTES (6772480ull * 4ull)  // 27,089,920 B

// ---------- v1 fallback ws layout ----------
#define V1_ACC 0
#define V1_X2  2048
#define V1_S2  4096
#define V1_W   54096

typedef __bf16 bf16x8 __attribute__((ext_vector_type(8)));
typedef __bf16 bf16x4 __attribute__((ext_vector_type(4)));
typedef float  f32x4  __attribute__((ext_vector_type(4)));
typedef unsigned int u32;

__device__ __forceinline__ float fast_exp2(float v) {
#if __has_builtin(__builtin_amdgcn_exp2f)
  return __builtin_amdgcn_exp2f(v);   // raw v_exp_f32
#else
  return exp2f(v);
#endif
}

// ============================================================
// FAST PATH
// ============================================================

// 16 lanes per row, 4 rows per wave (parallel, shallow shuffle chains).
// fp32->bf16 convert into ws, plus scaled norms and weights. Grid-stride.
__global__ __launch_bounds__(256) void svm_precvt2(
    const float* __restrict__ x, const float* __restrict__ s,
    const float* __restrict__ labels, const float* __restrict__ lambdas,
    float* __restrict__ ws) {
  const int l16 = threadIdx.x & 15;
  __bf16* xb = (__bf16*)(ws + WS_XB);
  __bf16* sb = (__bf16*)(ws + WS_SB);

  for (int row = blockIdx.x * 16 + (threadIdx.x >> 4);
       row < NPAD + BQ; row += gridDim.x * 16) {
    float4 v[4];
    const bool isS = row < NPAD;
    const float* src = isS ? (row < NPTS ? s + (size_t)row * DIM : nullptr)
                           : x + (size_t)(row - NPAD) * DIM;
    if (src) {
      #pragma unroll
      for (int c = 0; c < 4; ++c)
        v[c] = reinterpret_cast<const float4*>(src + l16 * 16)[c];
    } else {
      #pragma unroll
      for (int c = 0; c < 4; ++c) v[c] = make_float4(0.f, 0.f, 0.f, 0.f);
    }
    // convert + store 16 bf16 (32 B) contiguous per lane
    __bf16* dst = (isS ? sb + (size_t)row * DIM
                       : xb + (size_t)(row - NPAD) * DIM) + l16 * 16;
    #pragma unroll
    for (int c = 0; c < 4; ++c) {
      bf16x4 h = { (__bf16)v[c].x, (__bf16)v[c].y, (__bf16)v[c].z, (__bf16)v[c].w };
      *reinterpret_cast<bf16x4*>(dst + c * 4) = h;
    }
    float ss = 0.f;
    #pragma unroll
    for (int c = 0; c < 4; ++c)
      ss += v[c].x * v[c].x + v[c].y * v[c].y + v[c].z * v[c].z + v[c].w * v[c].w;
    ss += __shfl_xor(ss, 1);
    ss += __shfl_xor(ss, 2);
    ss += __shfl_xor(ss, 4);
    ss += __shfl_xor(ss, 8);
    if (l16 == 0) {
      if (isS) {
        ws[WS_S2 + row] = 0.5f * LOG2E * ss;
        float lam = (row < NPTS) ? lambdas[row] : 0.0f;
        float lab = (row < NPTS) ? labels[row] : 0.0f;
        ws[WS_W + row] = lab * (lam > 0.0f ? lam : 0.0f);
      } else {
        ws[WS_X2 + (row - NPAD)] = 0.5f * LOG2E * ss;
      }
    }
  }
}

// B-stationary persistent GEMM: each job = 64-row n-stripe held in registers;
// waves split M into quarters and stream A fragments straight from global (L2).
// No LDS staging, no barriers in the hot loop -> compiler interleaves
// VMEM loads with MFMA using fine-grained vmcnt (AITER-style).
__global__ __launch_bounds__(256, 2) void svm_main4(
    float* __restrict__ ws, u32* __restrict__ cnt) {
  __shared__ int sJob;

  const __bf16* xb = (const __bf16*)(ws + WS_XB);
  const __bf16* sb = (const __bf16*)(ws + WS_SB);
  const float* x2g = ws + WS_X2;
  const float* s2g = ws + WS_S2;
  const float* wg  = ws + WS_W;
  float* accOut    = ws + WS_ACC;

  const int t    = threadIdx.x;
  const int wave = t >> 6;
  const int lane = t & 63;
  const int quad = lane >> 4;
  const int l16  = lane & 15;
  const int mwave = wave * (BQ / 4);   // this wave's 512-row M quarter

  int job = blockIdx.x;
  while (job < NJOBS) {
    const int n0 = job * 64;

    // B fragments for the stripe: 4 ni x 8 kt x 16 B = 128 VGPR, loaded once.
    bf16x8 bfv[4][8];
    #pragma unroll
    for (int ni = 0; ni < 4; ++ni)
      #pragma unroll
      for (int kt = 0; kt < 8; ++kt)
        bfv[ni][kt] = *reinterpret_cast<const bf16x8*>(
            sb + (size_t)(n0 + ni * 16 + l16) * DIM + kt * BK + quad * 8);

    float s2t[4], wvv[4];
    #pragma unroll
    for (int ni = 0; ni < 4; ++ni) {
      int n = n0 + ni * 16 + l16;
      s2t[ni] = s2g[n];
      wvv[ni] = wg[n];
    }

    for (int i = 0; i < 16; ++i) {
      const int mb = mwave + i * 32;

      f32x4 acc[2][4];
      #pragma unroll
      for (int mi = 0; mi < 2; ++mi)
        #pragma unroll
        for (int ni = 0; ni < 4; ++ni)
          acc[mi][ni] = (f32x4)(0.0f);

      #pragma unroll
      for (int kt = 0; kt < 8; ++kt) {
        bf16x8 af0 = *reinterpret_cast<const bf16x8*>(
            xb + (size_t)(mb + l16) * DIM + kt * BK + quad * 8);
        bf16x8 af1 = *reinterpret_cast<const bf16x8*>(
            xb + (size_t)(mb + 16 + l16) * DIM + kt * BK + quad * 8);
        #pragma unroll
        for (int ni = 0; ni < 4; ++ni)
          acc[0][ni] = __builtin_amdgcn_mfma_f32_16x16x32_bf16(
              af0, bfv[ni][kt], acc[0][ni], 0, 0, 0);
        #pragma unroll
        for (int ni = 0; ni < 4; ++ni)
          acc[1][ni] = __builtin_amdgcn_mfma_f32_16x16x32_bf16(
              af1, bfv[ni][kt], acc[1][ni], 0, 0, 0);
      }

      // Epilogue: K*w = exp2(c*log2e - x2h - s2h) * w, reduce over the 16
      // n-columns (l16), one atomicAdd per output row.
      #pragma unroll
      for (int mi = 0; mi < 2; ++mi)
        #pragma unroll
        for (int reg = 0; reg < 4; ++reg) {
          int row = mb + mi * 16 + quad * 4 + reg;
          float xh = x2g[row];
          float p = 0.0f;
          #pragma unroll
          for (int ni = 0; ni < 4; ++ni)
            p += fast_exp2(__builtin_fmaf(acc[mi][ni][reg], LOG2E,
                                          -(xh + s2t[ni]))) * wvv[ni];
          p += __shfl_xor(p, 1);
          p += __shfl_xor(p, 2);
          p += __shfl_xor(p, 4);
          p += __shfl_xor(p, 8);
          if (l16 == 0) atomicAdd(&accOut[row], p);
        }
    }

    // steal next job (only barriers in the kernel; ~2 per job)
    __syncthreads();
    if (t == 0) sJob = GRID_MAIN + (int)atomicAdd(cnt, 1u);
    __syncthreads();
    job = sJob;
  }
}

// ============================================================
// V1 FALLBACK (used only if ws_size too small)
// ============================================================

__global__ __launch_bounds__(256) void svm_precompute(
    const float* __restrict__ x, const float* __restrict__ s,
    const float* __restrict__ labels, const float* __restrict__ lambdas,
    float* __restrict__ ws) {
  int wid  = blockIdx.x * 4 + (threadIdx.x >> 6);
  int lane = threadIdx.x & 63;
  const float* src;
  if (wid < NPTS)           src = s + (size_t)wid * DIM;
  else if (wid < NPTS + BQ) src = x + (size_t)(wid - NPTS) * DIM;
  else return;
  float4 v = reinterpret_cast<const float4*>(src)[lane];
  float ss = v.x * v.x + v.y * v.y + v.z * v.z + v.w * v.w;
  #pragma unroll
  for (int off = 32; off > 0; off >>= 1) ss += __shfl_xor(ss, off);
  if (lane == 0) {
    if (wid < NPTS) {
      ws[V1_S2 + wid] = ss;
      float lam = lambdas[wid];
      ws[V1_W + wid] = labels[wid] * (lam > 0.0f ? lam : 0.0f);
    } else {
      ws[V1_X2 + (wid - NPTS)] = ss;
    }
  }
}

__global__ __launch_bounds__(256) void svm_main(
    const float* __restrict__ x, const float* __restrict__ s,
    const float* __restrict__ ws) {
  __shared__ __bf16 sA[128 * BK];
  __shared__ __bf16 sB[128 * BK];

  const int t    = threadIdx.x;
  const int wave = t >> 6;
  const int lane = t & 63;
  const int quad = lane >> 4;
  const int l16  = lane & 15;
  const int wm   = (wave & 1) * 64;
  const int wn   = (wave >> 1) * 64;
  const int bRow0 = blockIdx.y * 128;
  const int n0    = blockIdx.x * 128;

  f32x4 acc[4][4];
  #pragma unroll
  for (int i = 0; i < 4; ++i)
    #pragma unroll
    for (int j = 0; j < 4; ++j)
      acc[i][j] = (f32x4)(0.0f);

  for (int kt = 0; kt < DIM / BK; ++kt) {
    const int k0 = kt * BK;
    __syncthreads();
    #pragma unroll
    for (int i = 0; i < 4; ++i) {
      int slot = t + i * 256;
      int r  = slot >> 3;
      int c4 = slot & 7;
      float4 va = reinterpret_cast<const float4*>(
          x + (size_t)(bRow0 + r) * DIM + k0)[c4];
      bf16x4 ha = { (__bf16)va.x, (__bf16)va.y, (__bf16)va.z, (__bf16)va.w };
      *reinterpret_cast<bf16x4*>(&sA[r * BK + c4 * 4]) = ha;

      int nrow = n0 + r;
      float4 vb = make_float4(0.f, 0.f, 0.f, 0.f);
      if (nrow < NPTS)
        vb = reinterpret_cast<const float4*>(
            s + (size_t)nrow * DIM + k0)[c4];
      bf16x4 hb = { (__bf16)vb.x, (__bf16)vb.y, (__bf16)vb.z, (__bf16)vb.w };
      *reinterpret_cast<bf16x4*>(&sB[r * BK + c4 * 4]) = hb;
    }
    __syncthreads();

    bf16x8 af[4], bfv[4];
    #pragma unroll
    for (int mi = 0; mi < 4; ++mi)
      af[mi] = *reinterpret_cast<const bf16x8*>(
          &sA[(wm + mi * 16 + l16) * BK + quad * 8]);
    #pragma unroll
    for (int ni = 0; ni < 4; ++ni)
      bfv[ni] = *reinterpret_cast<const bf16x8*>(
          &sB[(wn + ni * 16 + l16) * BK + quad * 8]);
    #pragma unroll
    for (int mi = 0; mi < 4; ++mi)
      #pragma unroll
      for (int ni = 0; ni < 4; ++ni)
        acc[mi][ni] = __builtin_amdgcn_mfma_f32_16x16x32_bf16(
            af[mi], bfv[ni], acc[mi][ni], 0, 0, 0);
  }

  const float* x2g = ws + V1_X2;
  const float* s2g = ws + V1_S2;
  const float* wg  = ws + V1_W;
  float* accOut    = (float*)ws + V1_ACC;

  float s2v[4], wv[4];
  #pragma unroll
  for (int ni = 0; ni < 4; ++ni) {
    int n = n0 + wn + ni * 16 + l16;
    bool ok = n < NPTS;
    s2v[ni] = ok ? s2g[n] : 0.0f;
    wv[ni]  = ok ? wg[n]  : 0.0f;
  }
  #pragma unroll
  for (int mi = 0; mi < 4; ++mi) {
    const int mbase = wm + mi * 16 + quad * 4;
    #pragma unroll
    for (int reg = 0; reg < 4; ++reg) {
      float x2r = x2g[bRow0 + mbase + reg];
      float ps = 0.0f;
      #pragma unroll
      for (int ni = 0; ni < 4; ++ni) {
        float cc = acc[mi][ni][reg];
        ps += __expf(__builtin_fmaf(-0.5f, x2r + s2v[ni], cc)) * wv[ni];
      }
      ps += __shfl_xor(ps, 1);
      ps += __shfl_xor(ps, 2);
      ps += __shfl_xor(ps, 4);
      ps += __shfl_xor(ps, 8);
      if (l16 == 0) atomicAdd(&accOut[bRow0 + mbase + reg], ps);
    }
  }
}

// ============================================================

__global__ __launch_bounds__(256) void svm_finalize(
    const float* __restrict__ ws, const float* __restrict__ bias,
    float* __restrict__ out) {
  int i = blockIdx.x * 256 + threadIdx.x;
  if (i < BQ) out[i] = tanhf(ws[i] + bias[0]);  // acc at offset 0 in both layouts
}

extern "C" void kernel_launch(void* const* d_in, const int* in_sizes, int n_in,
                              void* d_out, int out_size, void* d_ws, size_t ws_size,
                              hipStream_t stream) {
  const float* x       = (const float*)d_in[0];  // [2048, 256]
  const float* s       = (const float*)d_in[1];  // [50000, 256]
  const float* labels  = (const float*)d_in[2];  // [50000]
  const float* lambdas = (const float*)d_in[3];  // [50000]
  const float* bias    = (const float*)d_in[4];  // [1]
  float* out = (float*)d_out;                    // [2048]
  float* ws  = (float*)d_ws;

  hipMemsetAsync(ws, 0, BQ * sizeof(float), stream);   // acc = 0

  if (ws_size >= WS_TOTAL_BYTES) {
    // steal counter lives in d_out[0]; finalize overwrites it at the end
    hipMemsetAsync(d_out, 0, sizeof(u32), stream);
    svm_precvt2<<<512, 256, 0, stream>>>(x, s, labels, lambdas, ws);
    svm_main4<<<GRID_MAIN, 256, 0, stream>>>(ws, (u32*)d_out);
  } else {
    svm_precompute<<<(NPTS + BQ + 3) / 4, 256, 0, stream>>>(x, s, labels, lambdas, ws);
    dim3 grid(391, BQ / 128);
    svm_main<<<grid, 256, 0, stream>>>(x, s, ws);
  }
  svm_finalize<<<BQ / 256, 256, 0, stream>>>(ws, bias, out);
}

// Round 5
// 294.418 us; speedup vs baseline: 1.4706x; 1.4706x over previous
//
#include <hip/hip_runtime.h>
#include <hip/hip_bf16.h>

// Problem constants (fixed by the reference)
#define NPTS 50000   // N data points
#define DIM  256     // feature dim (K of the GEMM)
#define BQ   2048    // batch of queries (M of the GEMM)
#define NPAD 50048   // N padded to multiple of 128

#define BK   32
#define LOG2E 1.4426950408889634f

#define NCHUNK_TOT 3128   // NPAD/16 column-chunks
#define NGRP 32           // n-groups; grid = 16 m-tiles x 32 groups = 512

// ---------- fast-path ws layout (float offsets) ----------
//  acc   [0,      2048)
//  x2h   [2048,   4096)   0.5*log2e*||x||^2
//  s2h   [4096,  54144)   0.5*log2e*||s||^2 (NPAD)
//  w     [54144, 104192)  labels*relu(lambdas) (NPAD, 0-padded)
//  xb    [104192, 366336)   bf16 x
//  sb    [366336, 6772480)  bf16 s (NPAD rows, 0-padded)
#define WS_ACC 0
#define WS_X2  2048
#define WS_S2  4096
#define WS_W   54144
#define WS_XB  104192
#define WS_SB  366336
#define WS_TOTAL_BYTES (6772480ull * 4ull)  // 27,089,920 B

// ---------- v1 fallback ws layout ----------
#define V1_ACC 0
#define V1_X2  2048
#define V1_S2  4096
#define V1_W   54096

typedef __bf16 bf16x8 __attribute__((ext_vector_type(8)));
typedef __bf16 bf16x4 __attribute__((ext_vector_type(4)));
typedef float  f32x4  __attribute__((ext_vector_type(4)));
typedef unsigned int u32;

__device__ __forceinline__ float fast_exp2(float v) {
#if __has_builtin(__builtin_amdgcn_exp2f)
  return __builtin_amdgcn_exp2f(v);   // raw v_exp_f32
#else
  return exp2f(v);
#endif
}

// ============================================================
// FAST PATH
// ============================================================

// One wave per row (64 lanes x float4 = 256 floats, fully coalesced),
// grid-stride. Converts to bf16 in ws, computes scaled norms + weights.
// Blocks 0..7 also zero the 2048-float accumulator (replaces a memset).
__global__ __launch_bounds__(256) void svm_precvt3(
    const float* __restrict__ x, const float* __restrict__ s,
    const float* __restrict__ labels, const float* __restrict__ lambdas,
    float* __restrict__ ws) {
  const int lane = threadIdx.x & 63;
  __bf16* xb = (__bf16*)(ws + WS_XB);
  __bf16* sb = (__bf16*)(ws + WS_SB);

  if (blockIdx.x < 8) ws[WS_ACC + blockIdx.x * 256 + threadIdx.x] = 0.0f;

  for (int row = blockIdx.x * 4 + (threadIdx.x >> 6);
       row < NPAD + BQ; row += gridDim.x * 4) {
    const bool isS = row < NPAD;
    float4 v = make_float4(0.f, 0.f, 0.f, 0.f);
    if (isS) {
      if (row < NPTS)
        v = reinterpret_cast<const float4*>(s + (size_t)row * DIM)[lane];
    } else {
      v = reinterpret_cast<const float4*>(x + (size_t)(row - NPAD) * DIM)[lane];
    }
    __bf16* dst = isS ? sb + (size_t)row * DIM : xb + (size_t)(row - NPAD) * DIM;
    bf16x4 h = { (__bf16)v.x, (__bf16)v.y, (__bf16)v.z, (__bf16)v.w };
    *reinterpret_cast<bf16x4*>(dst + lane * 4) = h;

    float ss = v.x * v.x + v.y * v.y + v.z * v.z + v.w * v.w;
    #pragma unroll
    for (int off = 32; off > 0; off >>= 1) ss += __shfl_xor(ss, off);
    if (lane == 0) {
      if (isS) {
        ws[WS_S2 + row] = 0.5f * LOG2E * ss;
        float lam = (row < NPTS) ? lambdas[row] : 0.0f;
        float lab = (row < NPTS) ? labels[row] : 0.0f;
        ws[WS_W + row] = lab * (lam > 0.0f ? lam : 0.0f);
      } else {
        ws[WS_X2 + (row - NPAD)] = 0.5f * LOG2E * ss;
      }
    }
  }
}

// A-stationary register-streaming GEMM + fused RBF epilogue.
// Per wave: 32 m-rows of A pinned in 64 VGPRs; B streamed 16 n-rows at a
// time through a ping-pong register buffer (no LDS, no hot-loop barriers ->
// loads interleave with MFMA under fine-grained vmcnt). Grid 512 = 2/CU;
// amdgpu_waves_per_eu(2,2) pins the VGPR budget at 256 so nothing spills.
__global__ __attribute__((amdgpu_waves_per_eu(2, 2)))
__launch_bounds__(256) void svm_main5(float* __restrict__ ws) {
  const __bf16* xb = (const __bf16*)(ws + WS_XB);
  const __bf16* sb = (const __bf16*)(ws + WS_SB);
  const float* x2g = ws + WS_X2;
  const float* s2g = ws + WS_S2;
  const float* wg  = ws + WS_W;
  float* accOut    = ws + WS_ACC;

  const int t    = threadIdx.x;
  const int wave = t >> 6;
  const int lane = t & 63;
  const int quad = lane >> 4;
  const int l16  = lane & 15;

  const int g   = blockIdx.x & 31;          // n-group -> XCD g%8 shared by 16 siblings
  const int mt  = blockIdx.x >> 5;          // m-tile 0..15
  const int m0w = mt * 128 + wave * 32;     // this wave's 32 m-rows
  const int c0  = (NCHUNK_TOT * g) >> 5;
  const int c1  = (NCHUNK_TOT * (g + 1)) >> 5;

  // Pin A: 2 mi x 8 kt x 16 B = 64 VGPR, loaded once per block lifetime (L2-hot).
  bf16x8 af[2][8];
  #pragma unroll
  for (int mi = 0; mi < 2; ++mi)
    #pragma unroll
    for (int kt = 0; kt < 8; ++kt)
      af[mi][kt] = *reinterpret_cast<const bf16x8*>(
          xb + (size_t)(m0w + mi * 16 + l16) * DIM + kt * BK + quad * 8);

  float x2r[2][4];
  #pragma unroll
  for (int mi = 0; mi < 2; ++mi)
    #pragma unroll
    for (int r = 0; r < 4; ++r)
      x2r[mi][r] = x2g[m0w + mi * 16 + quad * 4 + r];

  float runAcc[2][4] = {{0.f, 0.f, 0.f, 0.f}, {0.f, 0.f, 0.f, 0.f}};

  auto loadB = [&](int c, bf16x8 (&dst)[8]) {
    const __bf16* p = sb + (size_t)(c * 16 + l16) * DIM + quad * 8;
    #pragma unroll
    for (int kt = 0; kt < 8; ++kt)
      dst[kt] = *reinterpret_cast<const bf16x8*>(p + kt * BK);
  };
  auto computeChunk = [&](const bf16x8 (&bv)[8], float s2, float w) {
    f32x4 a0 = (f32x4)(0.0f), a1 = (f32x4)(0.0f);
    #pragma unroll
    for (int kt = 0; kt < 8; ++kt) {
      a0 = __builtin_amdgcn_mfma_f32_16x16x32_bf16(af[0][kt], bv[kt], a0, 0, 0, 0);
      a1 = __builtin_amdgcn_mfma_f32_16x16x32_bf16(af[1][kt], bv[kt], a1, 0, 0, 0);
    }
    #pragma unroll
    for (int r = 0; r < 4; ++r) {
      runAcc[0][r] += fast_exp2(__builtin_fmaf(a0[r], LOG2E, -(x2r[0][r] + s2))) * w;
      runAcc[1][r] += fast_exp2(__builtin_fmaf(a1[r], LOG2E, -(x2r[1][r] + s2))) * w;
    }
  };

  // Software-pipelined ping-pong over chunks. Tail chunks re-run a valid
  // address with w=0 (contributes exactly 0; arguments stay finite-negative).
  bf16x8 b0[8], b1[8];
  float s2a, wa, s2b, wb;
  int c = c0;
  loadB(c, b0);
  s2a = s2g[c * 16 + l16];
  wa  = wg[c * 16 + l16];
  while (c < c1) {
    int cn = c + 1;
    int cl = (cn < c1) ? cn : c;
    loadB(cl, b1);
    s2b = s2g[cl * 16 + l16];
    wb  = (cn < c1) ? wg[cl * 16 + l16] : 0.0f;
    computeChunk(b0, s2a, wa);

    int cm  = c + 2;
    int cl2 = (cm < c1) ? cm : cl;
    loadB(cl2, b0);
    s2a = s2g[cl2 * 16 + l16];
    wa  = (cm < c1) ? wg[cl2 * 16 + l16] : 0.0f;
    computeChunk(b1, s2b, wb);
    c = cm;
  }

  // Final reduce over the 16 n-column lanes; one atomic per m-row per block.
  #pragma unroll
  for (int mi = 0; mi < 2; ++mi)
    #pragma unroll
    for (int r = 0; r < 4; ++r) {
      float v = runAcc[mi][r];
      v += __shfl_xor(v, 1);
      v += __shfl_xor(v, 2);
      v += __shfl_xor(v, 4);
      v += __shfl_xor(v, 8);
      if (l16 == 0)
        atomicAdd(&accOut[m0w + mi * 16 + quad * 4 + r], v);
    }
}

// ============================================================
// V1 FALLBACK (used only if ws_size too small)
// ============================================================

__global__ __launch_bounds__(256) void svm_precompute(
    const float* __restrict__ x, const float* __restrict__ s,
    const float* __restrict__ labels, const float* __restrict__ lambdas,
    float* __restrict__ ws) {
  int wid  = blockIdx.x * 4 + (threadIdx.x >> 6);
  int lane = threadIdx.x & 63;
  const float* src;
  if (wid < NPTS)           src = s + (size_t)wid * DIM;
  else if (wid < NPTS + BQ) src = x + (size_t)(wid - NPTS) * DIM;
  else return;
  float4 v = reinterpret_cast<const float4*>(src)[lane];
  float ss = v.x * v.x + v.y * v.y + v.z * v.z + v.w * v.w;
  #pragma unroll
  for (int off = 32; off > 0; off >>= 1) ss += __shfl_xor(ss, off);
  if (lane == 0) {
    if (wid < NPTS) {
      ws[V1_S2 + wid] = ss;
      float lam = lambdas[wid];
      ws[V1_W + wid] = labels[wid] * (lam > 0.0f ? lam : 0.0f);
    } else {
      ws[V1_X2 + (wid - NPTS)] = ss;
    }
  }
}

__global__ __launch_bounds__(256) void svm_main(
    const float* __restrict__ x, const float* __restrict__ s,
    const float* __restrict__ ws) {
  __shared__ __bf16 sA[128 * BK];
  __shared__ __bf16 sB[128 * BK];

  const int t    = threadIdx.x;
  const int wave = t >> 6;
  const int lane = t & 63;
  const int quad = lane >> 4;
  const int l16  = lane & 15;
  const int wm   = (wave & 1) * 64;
  const int wn   = (wave >> 1) * 64;
  const int bRow0 = blockIdx.y * 128;
  const int n0    = blockIdx.x * 128;

  f32x4 acc[4][4];
  #pragma unroll
  for (int i = 0; i < 4; ++i)
    #pragma unroll
    for (int j = 0; j < 4; ++j)
      acc[i][j] = (f32x4)(0.0f);

  for (int kt = 0; kt < DIM / BK; ++kt) {
    const int k0 = kt * BK;
    __syncthreads();
    #pragma unroll
    for (int i = 0; i < 4; ++i) {
      int slot = t + i * 256;
      int r  = slot >> 3;
      int c4 = slot & 7;
      float4 va = reinterpret_cast<const float4*>(
          x + (size_t)(bRow0 + r) * DIM + k0)[c4];
      bf16x4 ha = { (__bf16)va.x, (__bf16)va.y, (__bf16)va.z, (__bf16)va.w };
      *reinterpret_cast<bf16x4*>(&sA[r * BK + c4 * 4]) = ha;

      int nrow = n0 + r;
      float4 vb = make_float4(0.f, 0.f, 0.f, 0.f);
      if (nrow < NPTS)
        vb = reinterpret_cast<const float4*>(
            s + (size_t)nrow * DIM + k0)[c4];
      bf16x4 hb = { (__bf16)vb.x, (__bf16)vb.y, (__bf16)vb.z, (__bf16)vb.w };
      *reinterpret_cast<bf16x4*>(&sB[r * BK + c4 * 4]) = hb;
    }
    __syncthreads();

    bf16x8 af[4], bfv[4];
    #pragma unroll
    for (int mi = 0; mi < 4; ++mi)
      af[mi] = *reinterpret_cast<const bf16x8*>(
          &sA[(wm + mi * 16 + l16) * BK + quad * 8]);
    #pragma unroll
    for (int ni = 0; ni < 4; ++ni)
      bfv[ni] = *reinterpret_cast<const bf16x8*>(
          &sB[(wn + ni * 16 + l16) * BK + quad * 8]);
    #pragma unroll
    for (int mi = 0; mi < 4; ++mi)
      #pragma unroll
      for (int ni = 0; ni < 4; ++ni)
        acc[mi][ni] = __builtin_amdgcn_mfma_f32_16x16x32_bf16(
            af[mi], bfv[ni], acc[mi][ni], 0, 0, 0);
  }

  const float* x2g = ws + V1_X2;
  const float* s2g = ws + V1_S2;
  const float* wg  = ws + V1_W;
  float* accOut    = (float*)ws + V1_ACC;

  float s2v[4], wv[4];
  #pragma unroll
  for (int ni = 0; ni < 4; ++ni) {
    int n = n0 + wn + ni * 16 + l16;
    bool ok = n < NPTS;
    s2v[ni] = ok ? s2g[n] : 0.0f;
    wv[ni]  = ok ? wg[n]  : 0.0f;
  }
  #pragma unroll
  for (int mi = 0; mi < 4; ++mi) {
    const int mbase = wm + mi * 16 + quad * 4;
    #pragma unroll
    for (int reg = 0; reg < 4; ++reg) {
      float x2r = x2g[bRow0 + mbase + reg];
      float ps = 0.0f;
      #pragma unroll
      for (int ni = 0; ni < 4; ++ni) {
        float cc = acc[mi][ni][reg];
        ps += __expf(__builtin_fmaf(-0.5f, x2r + s2v[ni], cc)) * wv[ni];
      }
      ps += __shfl_xor(ps, 1);
      ps += __shfl_xor(ps, 2);
      ps += __shfl_xor(ps, 4);
      ps += __shfl_xor(ps, 8);
      if (l16 == 0) atomicAdd(&accOut[bRow0 + mbase + reg], ps);
    }
  }
}

// ============================================================

__global__ __launch_bounds__(256) void svm_finalize(
    const float* __restrict__ ws, const float* __restrict__ bias,
    float* __restrict__ out) {
  int i = blockIdx.x * 256 + threadIdx.x;
  if (i < BQ) out[i] = tanhf(ws[i] + bias[0]);  // acc at offset 0 in both layouts
}

extern "C" void kernel_launch(void* const* d_in, const int* in_sizes, int n_in,
                              void* d_out, int out_size, void* d_ws, size_t ws_size,
                              hipStream_t stream) {
  const float* x       = (const float*)d_in[0];  // [2048, 256]
  const float* s       = (const float*)d_in[1];  // [50000, 256]
  const float* labels  = (const float*)d_in[2];  // [50000]
  const float* lambdas = (const float*)d_in[3];  // [50000]
  const float* bias    = (const float*)d_in[4];  // [1]
  float* out = (float*)d_out;                    // [2048]
  float* ws  = (float*)d_ws;

  if (ws_size >= WS_TOTAL_BYTES) {
    // precvt3 zeroes the accumulator region itself (blocks 0..7)
    svm_precvt3<<<512, 256, 0, stream>>>(x, s, labels, lambdas, ws);
    svm_main5<<<16 * NGRP, 256, 0, stream>>>(ws);
  } else {
    hipMemsetAsync(ws, 0, BQ * sizeof(float), stream);
    svm_precompute<<<(NPTS + BQ + 3) / 4, 256, 0, stream>>>(x, s, labels, lambdas, ws);
    dim3 grid(391, BQ / 128);
    svm_main<<<grid, 256, 0, stream>>>(x, s, ws);
  }
  svm_finalize<<<BQ / 256, 256, 0, stream>>>(ws, bias, out);
}

// Round 6
// 159.324 us; speedup vs baseline: 2.7176x; 1.8479x over previous
//
#include <hip/hip_runtime.h>
#include <hip/hip_bf16.h>

// Problem constants (fixed by the reference)
#define NPTS 50000   // N data points
#define DIM  256     // feature dim (K of the GEMM)
#define BQ   2048    // batch of queries (M of the GEMM)
#define NPAD 50048   // N padded to multiple of 128

#define TILE 128
#define BK   32
#define NCHUNKS 391  // NPAD/128
#define NGROUPS 32   // grid = 16 m-tiles x 32 groups
#define LOG2E 1.4426950408889634f

// ---------- fast-path ws layout (float offsets) ----------
//  acc   [0,      2048)
//  x2h   [2048,   4096)   0.5*log2e*||x||^2
//  s2h   [4096,  54144)   0.5*log2e*||s||^2 (NPAD)
//  w     [54144, 104192)  labels*relu(lambdas) (NPAD, 0-padded)
//  xb    [104192, 366336)   bf16 x
//  sb    [366336, 6772480)  bf16 s (NPAD rows, 0-padded)
#define WS_ACC 0
#define WS_X2  2048
#define WS_S2  4096
#define WS_W   54144
#define WS_XB  104192
#define WS_SB  366336
#define WS_TOTAL_BYTES (6772480ull * 4ull)  // 27,089,920 B

// ---------- v1 fallback ws layout ----------
#define V1_ACC 0
#define V1_X2  2048
#define V1_S2  4096
#define V1_W   54096

typedef __bf16 bf16x8 __attribute__((ext_vector_type(8)));
typedef __bf16 bf16x4 __attribute__((ext_vector_type(4)));
typedef float  f32x4  __attribute__((ext_vector_type(4)));
typedef unsigned int u32;

__device__ __forceinline__ float fast_exp2(float v) {
#if __has_builtin(__builtin_amdgcn_exp2f)
  return __builtin_amdgcn_exp2f(v);   // raw v_exp_f32
#else
  return exp2f(v);
#endif
}

__device__ __forceinline__ void async_copy16(const __bf16* g, __bf16* l) {
  __builtin_amdgcn_global_load_lds(
      (const __attribute__((address_space(1))) u32*)g,
      (__attribute__((address_space(3))) u32*)l, 16, 0, 0);
}

// ============================================================
// FAST PATH
// ============================================================

// One wave per row: fp32->bf16 convert into ws, plus scaled norms and w.
// Blocks 0..7 also zero the accumulator (replaces a memset dispatch).
__global__ __launch_bounds__(256) void svm_precvt4(
    const float* __restrict__ x, const float* __restrict__ s,
    const float* __restrict__ labels, const float* __restrict__ lambdas,
    float* __restrict__ ws) {
  const int wid  = blockIdx.x * 4 + (threadIdx.x >> 6);
  const int lane = threadIdx.x & 63;
  __bf16* xb = (__bf16*)(ws + WS_XB);
  __bf16* sb = (__bf16*)(ws + WS_SB);

  if (blockIdx.x < 8) ws[WS_ACC + blockIdx.x * 256 + threadIdx.x] = 0.0f;

  if (wid < NPAD) {
    float4 v = make_float4(0.f, 0.f, 0.f, 0.f);
    if (wid < NPTS)
      v = reinterpret_cast<const float4*>(s + (size_t)wid * DIM)[lane];
    bf16x4 h = { (__bf16)v.x, (__bf16)v.y, (__bf16)v.z, (__bf16)v.w };
    *reinterpret_cast<bf16x4*>(sb + (size_t)wid * DIM + lane * 4) = h;
    float ss = v.x * v.x + v.y * v.y + v.z * v.z + v.w * v.w;
    #pragma unroll
    for (int off = 32; off > 0; off >>= 1) ss += __shfl_xor(ss, off);
    if (lane == 0) {
      ws[WS_S2 + wid] = 0.5f * LOG2E * ss;
      float lam = (wid < NPTS) ? lambdas[wid] : 0.0f;
      float lab = (wid < NPTS) ? labels[wid] : 0.0f;
      ws[WS_W + wid] = lab * (lam > 0.0f ? lam : 0.0f);
    }
  } else if (wid < NPAD + BQ) {
    int r = wid - NPAD;
    float4 v = reinterpret_cast<const float4*>(x + (size_t)r * DIM)[lane];
    bf16x4 h = { (__bf16)v.x, (__bf16)v.y, (__bf16)v.z, (__bf16)v.w };
    *reinterpret_cast<bf16x4*>(xb + (size_t)r * DIM + lane * 4) = h;
    float ss = v.x * v.x + v.y * v.y + v.z * v.z + v.w * v.w;
    #pragma unroll
    for (int off = 32; off > 0; off >>= 1) ss += __shfl_xor(ss, off);
    if (lane == 0) ws[WS_X2 + r] = 0.5f * LOG2E * ss;
  }
}

// main3 structure + (a) 2-way XOR-swizzled B LDS layout (kills the 64B-stride
// bank conflicts that bounded main3), (b) asm-pinned A fragments (no remat).
// Block = 128-row m-stripe, streams ~12 n-chunks of 128 rows.
__global__ __launch_bounds__(256, 2) void svm_main6(float* __restrict__ ws) {
  // [kt][n][32k] with 16B slot swizzle: slot(n,c) = c ^ ((n>>1)&3)
  __shared__ __bf16 sB[8 * 128 * 32];  // 64 KB

  const __bf16* xb = (const __bf16*)(ws + WS_XB);
  const __bf16* sb = (const __bf16*)(ws + WS_SB);
  const float* x2g = ws + WS_X2;
  const float* s2g = ws + WS_S2;
  const float* wg  = ws + WS_W;
  float* accOut    = ws + WS_ACC;

  const int t    = threadIdx.x;
  const int wave = t >> 6;
  const int lane = t & 63;
  const int quad = lane >> 4;
  const int l16  = lane & 15;
  const int bid  = blockIdx.x;
  const int g    = bid & 31;        // n-group: 16 m-siblings share XCD g%8
  const int mt   = bid >> 5;        // m-tile 0..15
  const int m0   = mt * TILE;
  const int c0   = g * 12 + (g < 7 ? g : 7);
  const int cnt  = 12 + (g < 7 ? 1 : 0);

  // A fragments: 2 mi x 8 kt x 16 B = 64 VGPR, loaded once, pinned opaque.
  f32x4 afr[2][8];
  #pragma unroll
  for (int mi = 0; mi < 2; ++mi)
    #pragma unroll
    for (int kt = 0; kt < 8; ++kt)
      afr[mi][kt] = *reinterpret_cast<const f32x4*>(
          xb + (size_t)(m0 + wave * 32 + mi * 16 + l16) * DIM + kt * BK + quad * 8);
  #pragma unroll
  for (int mi = 0; mi < 2; ++mi)
    #pragma unroll
    for (int kt = 0; kt < 8; ++kt)
      asm volatile("" : "+v"(afr[mi][kt]));  // opaque: no remat, stays in VGPRs

  float x2r[2][4];
  #pragma unroll
  for (int mi = 0; mi < 2; ++mi)
    #pragma unroll
    for (int r = 0; r < 4; ++r)
      x2r[mi][r] = x2g[m0 + wave * 32 + mi * 16 + quad * 4 + r];

  float runAcc[2][4] = {{0.f, 0.f, 0.f, 0.f}, {0.f, 0.f, 0.f, 0.f}};

  // staging source swizzle is lane-only: chunk fetched = (l&3) ^ ((l>>3)&3)
  const int srcswz = ((lane & 3) ^ ((lane >> 3) & 3)) * 8;  // bf16 elems
  // read-side swizzled k-slot for this lane's B fragment
  const int rdswz = (quad ^ ((l16 >> 1) & 3)) * 8;          // bf16 elems

  for (int c = c0; c < c0 + cnt; ++c) {
    __syncthreads();  // prior chunk's LDS reads done

    // epilogue operands for this chunk — issue before staging so their
    // latency hides under the staging drain
    float s2t[8], wvv[8];
    #pragma unroll
    for (int ni = 0; ni < 8; ++ni) {
      int n = c * TILE + ni * 16 + l16;
      s2t[ni] = s2g[n];
      wvv[ni] = wg[n];
    }

    // Stage B chunk [kt][n][32k], swizzled. 16 instrs/wave, 1 KB each.
    #pragma unroll
    for (int i = 0; i < 16; ++i) {
      int chunk = wave * 16 + i;           // 0..63
      int kt = chunk >> 3;
      int nb = (chunk & 7) * 16;
      const __bf16* src = sb + (size_t)(c * TILE + nb + (lane >> 2)) * DIM
                             + kt * BK + srcswz;
      async_copy16(src, &sB[kt * 4096 + nb * BK] + lane * 8);
    }
    __syncthreads();  // vmcnt drain

    f32x4 acc[2][8];
    #pragma unroll
    for (int mi = 0; mi < 2; ++mi)
      #pragma unroll
      for (int ni = 0; ni < 8; ++ni)
        acc[mi][ni] = (f32x4)(0.0f);

    #pragma unroll
    for (int kt = 0; kt < 8; ++kt) {
      bf16x8 bfv[8];
      #pragma unroll
      for (int ni = 0; ni < 8; ++ni)
        bfv[ni] = *reinterpret_cast<const bf16x8*>(
            &sB[kt * 4096 + (ni * 16 + l16) * BK + rdswz]);
      #pragma unroll
      for (int mi = 0; mi < 2; ++mi)
        #pragma unroll
        for (int ni = 0; ni < 8; ++ni)
          acc[mi][ni] = __builtin_amdgcn_mfma_f32_16x16x32_bf16(
              __builtin_bit_cast(bf16x8, afr[mi][kt]), bfv[ni],
              acc[mi][ni], 0, 0, 0);
    }

    // Epilogue: K*w = exp2(c*log2e - x2h - s2h) * w, accumulate in registers.
    #pragma unroll
    for (int mi = 0; mi < 2; ++mi)
      #pragma unroll
      for (int reg = 0; reg < 4; ++reg) {
        float xh = x2r[mi][reg];
        float p = 0.0f;
        #pragma unroll
        for (int ni = 0; ni < 8; ++ni)
          p += fast_exp2(__builtin_fmaf(acc[mi][ni][reg], LOG2E,
                                        -(xh + s2t[ni]))) * wvv[ni];
        runAcc[mi][reg] += p;
      }
  }

  // one reduction + atomic per output row per block
  #pragma unroll
  for (int mi = 0; mi < 2; ++mi)
    #pragma unroll
    for (int reg = 0; reg < 4; ++reg) {
      float v = runAcc[mi][reg];
      v += __shfl_xor(v, 1);
      v += __shfl_xor(v, 2);
      v += __shfl_xor(v, 4);
      v += __shfl_xor(v, 8);
      if (l16 == 0)
        atomicAdd(&accOut[m0 + wave * 32 + mi * 16 + quad * 4 + reg], v);
    }
}

// ============================================================
// V1 FALLBACK (used only if ws_size too small)
// ============================================================

__global__ __launch_bounds__(256) void svm_precompute(
    const float* __restrict__ x, const float* __restrict__ s,
    const float* __restrict__ labels, const float* __restrict__ lambdas,
    float* __restrict__ ws) {
  int wid  = blockIdx.x * 4 + (threadIdx.x >> 6);
  int lane = threadIdx.x & 63;
  const float* src;
  if (wid < NPTS)           src = s + (size_t)wid * DIM;
  else if (wid < NPTS + BQ) src = x + (size_t)(wid - NPTS) * DIM;
  else return;
  float4 v = reinterpret_cast<const float4*>(src)[lane];
  float ss = v.x * v.x + v.y * v.y + v.z * v.z + v.w * v.w;
  #pragma unroll
  for (int off = 32; off > 0; off >>= 1) ss += __shfl_xor(ss, off);
  if (lane == 0) {
    if (wid < NPTS) {
      ws[V1_S2 + wid] = ss;
      float lam = lambdas[wid];
      ws[V1_W + wid] = labels[wid] * (lam > 0.0f ? lam : 0.0f);
    } else {
      ws[V1_X2 + (wid - NPTS)] = ss;
    }
  }
}

__global__ __launch_bounds__(256) void svm_main(
    const float* __restrict__ x, const float* __restrict__ s,
    const float* __restrict__ ws) {
  __shared__ __bf16 sA[128 * BK];
  __shared__ __bf16 sB[128 * BK];

  const int t    = threadIdx.x;
  const int wave = t >> 6;
  const int lane = t & 63;
  const int quad = lane >> 4;
  const int l16  = lane & 15;
  const int wm   = (wave & 1) * 64;
  const int wn   = (wave >> 1) * 64;
  const int bRow0 = blockIdx.y * 128;
  const int n0    = blockIdx.x * 128;

  f32x4 acc[4][4];
  #pragma unroll
  for (int i = 0; i < 4; ++i)
    #pragma unroll
    for (int j = 0; j < 4; ++j)
      acc[i][j] = (f32x4)(0.0f);

  for (int kt = 0; kt < DIM / BK; ++kt) {
    const int k0 = kt * BK;
    __syncthreads();
    #pragma unroll
    for (int i = 0; i < 4; ++i) {
      int slot = t + i * 256;
      int r  = slot >> 3;
      int c4 = slot & 7;
      float4 va = reinterpret_cast<const float4*>(
          x + (size_t)(bRow0 + r) * DIM + k0)[c4];
      bf16x4 ha = { (__bf16)va.x, (__bf16)va.y, (__bf16)va.z, (__bf16)va.w };
      *reinterpret_cast<bf16x4*>(&sA[r * BK + c4 * 4]) = ha;

      int nrow = n0 + r;
      float4 vb = make_float4(0.f, 0.f, 0.f, 0.f);
      if (nrow < NPTS)
        vb = reinterpret_cast<const float4*>(
            s + (size_t)nrow * DIM + k0)[c4];
      bf16x4 hb = { (__bf16)vb.x, (__bf16)vb.y, (__bf16)vb.z, (__bf16)vb.w };
      *reinterpret_cast<bf16x4*>(&sB[r * BK + c4 * 4]) = hb;
    }
    __syncthreads();

    bf16x8 af[4], bfv[4];
    #pragma unroll
    for (int mi = 0; mi < 4; ++mi)
      af[mi] = *reinterpret_cast<const bf16x8*>(
          &sA[(wm + mi * 16 + l16) * BK + quad * 8]);
    #pragma unroll
    for (int ni = 0; ni < 4; ++ni)
      bfv[ni] = *reinterpret_cast<const bf16x8*>(
          &sB[(wn + ni * 16 + l16) * BK + quad * 8]);
    #pragma unroll
    for (int mi = 0; mi < 4; ++mi)
      #pragma unroll
      for (int ni = 0; ni < 4; ++ni)
        acc[mi][ni] = __builtin_amdgcn_mfma_f32_16x16x32_bf16(
            af[mi], bfv[ni], acc[mi][ni], 0, 0, 0);
  }

  const float* x2g = ws + V1_X2;
  const float* s2g = ws + V1_S2;
  const float* wg  = ws + V1_W;
  float* accOut    = (float*)ws + V1_ACC;

  float s2v[4], wv[4];
  #pragma unroll
  for (int ni = 0; ni < 4; ++ni) {
    int n = n0 + wn + ni * 16 + l16;
    bool ok = n < NPTS;
    s2v[ni] = ok ? s2g[n] : 0.0f;
    wv[ni]  = ok ? wg[n]  : 0.0f;
  }
  #pragma unroll
  for (int mi = 0; mi < 4; ++mi) {
    const int mbase = wm + mi * 16 + quad * 4;
    #pragma unroll
    for (int reg = 0; reg < 4; ++reg) {
      float x2r = x2g[bRow0 + mbase + reg];
      float ps = 0.0f;
      #pragma unroll
      for (int ni = 0; ni < 4; ++ni) {
        float cc = acc[mi][ni][reg];
        ps += __expf(__builtin_fmaf(-0.5f, x2r + s2v[ni], cc)) * wv[ni];
      }
      ps += __shfl_xor(ps, 1);
      ps += __shfl_xor(ps, 2);
      ps += __shfl_xor(ps, 4);
      ps += __shfl_xor(ps, 8);
      if (l16 == 0) atomicAdd(&accOut[bRow0 + mbase + reg], ps);
    }
  }
}

// ============================================================

__global__ __launch_bounds__(256) void svm_finalize(
    const float* __restrict__ ws, const float* __restrict__ bias,
    float* __restrict__ out) {
  int i = blockIdx.x * 256 + threadIdx.x;
  if (i < BQ) out[i] = tanhf(ws[i] + bias[0]);  // acc at offset 0 in both layouts
}

extern "C" void kernel_launch(void* const* d_in, const int* in_sizes, int n_in,
                              void* d_out, int out_size, void* d_ws, size_t ws_size,
                              hipStream_t stream) {
  const float* x       = (const float*)d_in[0];  // [2048, 256]
  const float* s       = (const float*)d_in[1];  // [50000, 256]
  const float* labels  = (const float*)d_in[2];  // [50000]
  const float* lambdas = (const float*)d_in[3];  // [50000]
  const float* bias    = (const float*)d_in[4];  // [1]
  float* out = (float*)d_out;                    // [2048]
  float* ws  = (float*)d_ws;

  if (ws_size >= WS_TOTAL_BYTES) {
    // precvt4 zeroes the accumulator region itself (blocks 0..7)
    svm_precvt4<<<(NPAD + BQ + 3) / 4, 256, 0, stream>>>(x, s, labels, lambdas, ws);
    svm_main6<<<16 * NGROUPS, 256, 0, stream>>>(ws);
  } else {
    hipMemsetAsync(ws, 0, BQ * sizeof(float), stream);
    svm_precompute<<<(NPTS + BQ + 3) / 4, 256, 0, stream>>>(x, s, labels, lambdas, ws);
    dim3 grid(391, BQ / 128);
    svm_main<<<grid, 256, 0, stream>>>(x, s, ws);
  }
  svm_finalize<<<BQ / 256, 256, 0, stream>>>(ws, bias, out);
}